// Round 8
// baseline (221.340 us; speedup 1.0000x reference)
//
#include <hip/hip_runtime.h>

// SelfAttention: out = softmax((x Wq^T)(x Wk^T)^T / 32) (x Wv^T)
// N=4096, D=1024, f32 in/out; bf16 MFMA compute.
// GEMM v8 = v7 core (256x128 tile, 4 waves, wave-tile 128x64, BK=32,
// 2-buffer 48 KiB LDS, prefetch-1 + counted vmcnt(6), conflict-free XOR
// swizzle, XCD block swizzle, 2 blocks/CU) + fused split-K reduction in the
// PV epilogue via per-tile atomic flags (release/acquire), removing the
// separate reduce pass. Both partials go through bf16 rounding so the
// result is independent of which block finishes last (deterministic).

typedef __attribute__((ext_vector_type(8))) __bf16 bf16x8;
typedef __attribute__((ext_vector_type(4))) float floatx4;

#define GLB_AS __attribute__((address_space(1)))
#define LDS_AS __attribute__((address_space(3)))

static __device__ __forceinline__ unsigned short f2bf_u16(float f) {
  union { float f; unsigned u; } x; x.f = f;
  unsigned r = x.u;
  r += 0x7fffu + ((r >> 16) & 1u);   // RNE
  return (unsigned short)(r >> 16);
}
static __device__ __forceinline__ float bf2f(unsigned short u) {
  union { unsigned u; float f; } x; x.u = ((unsigned)u) << 16; return x.f;
}

// ---------------- fused cast f32 -> bf16 (x + Wq + Wk + Wv) + counter zero ----------------
__global__ __launch_bounds__(256) void cast_all(const float* __restrict__ x,
                                                const float* __restrict__ Wq,
                                                const float* __restrict__ Wk,
                                                const float* __restrict__ Wv,
                                                unsigned short* __restrict__ xb,
                                                unsigned short* __restrict__ wb,
                                                int* __restrict__ cnt) {
  const int NX4 = 4096 * 1024 / 4;
  const int NW4 = 1024 * 1024 / 4;
  if (blockIdx.x == 7168) {                  // tail block: zero the PV tile counters
    if (threadIdx.x < 128) cnt[threadIdx.x] = 0;
    return;
  }
  const int i = blockIdx.x * 256 + threadIdx.x;   // float4 index
  const float* src; unsigned short* dst; int k;
  if (i < NX4)                { src = x;  dst = xb;                   k = i; }
  else if (i < NX4 + NW4)     { src = Wq; dst = wb;                   k = i - NX4; }
  else if (i < NX4 + 2 * NW4) { src = Wk; dst = wb + 1024 * 1024;     k = i - NX4 - NW4; }
  else                        { src = Wv; dst = wb + 2 * 1024 * 1024; k = i - NX4 - 2 * NW4; }
  float4 v = reinterpret_cast<const float4*>(src)[k];
  ushort4 o = make_ushort4(f2bf_u16(v.x), f2bf_u16(v.y), f2bf_u16(v.z), f2bf_u16(v.w));
  reinterpret_cast<ushort4*>(dst)[k] = o;
}

// ---------------- collapse rsp[64][4096] -> rs[4096] ----------------
__global__ __launch_bounds__(256) void collapse_rs(const float* __restrict__ rsp,
                                                   float* __restrict__ rs) {
  const int r = blockIdx.x * 256 + threadIdx.x;
  float s = 0.f;
#pragma unroll
  for (int j = 0; j < 64; ++j) s += rsp[j * 4096 + r];
  rs[r] = s;
}

// ---------------- GEMM: C[M,N] = epi(scale * A[M,K] * B[N,K]^T) ----------------
// EPI: 0 = PV  (bf16 partial + atomic-flag fused reduction -> f32 out)
//      2 = S   (bf16 store of exp to c[0]; per-(colblock,wave) row-sum partials to c[1])
//      3 = QKV (col0<2048: bf16 -> qkb c[0]; col0>=2048: transposed -> vT c[1])
struct GemmOuts { void* c[5]; int ldc0; };

template <int EPI>
__global__ __launch_bounds__(256, 2) void gemm_bt(const unsigned short* __restrict__ A,
                                                  const unsigned short* __restrict__ B,
                                                  GemmOuts outs, int lda, int ldb,
                                                  int klen, float scale) {
  // LDS: 2 bufs x (A [256][32] + B [128][32]) = 24576 elems = 48 KiB
  __shared__ unsigned short sh[24576];
  __shared__ int lf;
  const int t = threadIdx.x;
  const int w = t >> 6, lane = t & 63;
  const int wm = w >> 1, wn = w & 1;        // 2x2 wave grid, wave tile 128x64
  // XCD-aware bijective block swizzle (nwg % 8 == 0 for all grids here)
  const int gx = gridDim.x;
  const int nwg = gx * gridDim.y;
  int bid = blockIdx.y * gx + blockIdx.x;
  bid = (bid & 7) * (nwg >> 3) + (bid >> 3);
  const int row0 = (bid / gx) * 256;
  const int col0 = (bid % gx) * 128;
  const int z = blockIdx.z;
  const int kstart = z * klen;
  const int NT = klen >> 5;                 // K-tiles of 32 (NT >= 2)

  // staging: 6 x 16B per thread per K-tile. Inverse-swizzled global col (rule 21).
  const int srow = t >> 2;                                  // 0..63
  const int scbe = (((t & 3) ^ ((t >> 3) & 3)) << 3);       // swizzled src col (elems)
  const unsigned short* gA0 = A + (size_t)(row0 + srow) * lda + kstart + scbe;
  const unsigned short* gA1 = gA0 + (size_t)64 * lda;
  const unsigned short* gA2 = gA0 + (size_t)128 * lda;
  const unsigned short* gA3 = gA0 + (size_t)192 * lda;
  const unsigned short* gB0 = B + (size_t)(col0 + srow) * ldb + kstart + scbe;
  const unsigned short* gB1 = gB0 + (size_t)64 * ldb;

#define STAGE(tl_) do { \
    const int bb_ = ((tl_) & 1) * 12288; \
    __builtin_amdgcn_global_load_lds((const GLB_AS void*)(gA0 + (tl_) * 32), \
        (LDS_AS void*)&sh[bb_ + t * 8], 16, 0, 0); \
    __builtin_amdgcn_global_load_lds((const GLB_AS void*)(gA1 + (tl_) * 32), \
        (LDS_AS void*)&sh[bb_ + 2048 + t * 8], 16, 0, 0); \
    __builtin_amdgcn_global_load_lds((const GLB_AS void*)(gA2 + (tl_) * 32), \
        (LDS_AS void*)&sh[bb_ + 4096 + t * 8], 16, 0, 0); \
    __builtin_amdgcn_global_load_lds((const GLB_AS void*)(gA3 + (tl_) * 32), \
        (LDS_AS void*)&sh[bb_ + 6144 + t * 8], 16, 0, 0); \
    __builtin_amdgcn_global_load_lds((const GLB_AS void*)(gB0 + (tl_) * 32), \
        (LDS_AS void*)&sh[bb_ + 8192 + t * 8], 16, 0, 0); \
    __builtin_amdgcn_global_load_lds((const GLB_AS void*)(gB1 + (tl_) * 32), \
        (LDS_AS void*)&sh[bb_ + 10240 + t * 8], 16, 0, 0); \
  } while (0)

  // ds_read element offsets (swizzled; conflict-free family, 0 conflicts r2-r7)
  const int fr = lane & 15;
  const int sg = (((lane >> 4) ^ ((lane >> 1) & 3)) << 3);
  int aofs[8], bofs[4];
#pragma unroll
  for (int mf = 0; mf < 8; ++mf) aofs[mf] = ((wm * 128 + mf * 16 + fr) << 5) + sg;
#pragma unroll
  for (int nf = 0; nf < 4; ++nf) bofs[nf] = 8192 + ((wn * 64 + nf * 16 + fr) << 5) + sg;

  floatx4 acc[8][4] = {};

  STAGE(0);

  for (int tile = 0; tile < NT; ++tile) {
    if (tile + 1 < NT) {
      STAGE(tile + 1);
      asm volatile("s_waitcnt vmcnt(6)" ::: "memory");   // tile's own 6 loads landed
    } else {
      asm volatile("s_waitcnt vmcnt(0)" ::: "memory");
    }
    __builtin_amdgcn_s_barrier();   // buf[tile&1] ready for all waves

    const int bo = (tile & 1) * 12288;
    bf16x8 af[8], bf[4];
#pragma unroll
    for (int mf = 0; mf < 8; ++mf) af[mf] = *(const bf16x8*)&sh[bo + aofs[mf]];
#pragma unroll
    for (int nf = 0; nf < 4; ++nf) bf[nf] = *(const bf16x8*)&sh[bo + bofs[nf]];
#pragma unroll
    for (int mf = 0; mf < 8; ++mf)
#pragma unroll
      for (int nf = 0; nf < 4; ++nf)
        acc[mf][nf] = __builtin_amdgcn_mfma_f32_16x16x32_bf16(af[mf], bf[nf], acc[mf][nf], 0, 0, 0);

    __builtin_amdgcn_s_barrier();   // all waves done reading buf[tile&1]
  }
#undef STAGE

  // epilogue: C col = lane&15, row = (lane>>4)*4 + r  [m89-verified]
  const int er = (lane >> 4) * 4;
  const int ec = lane & 15;

  if (EPI == 0) {
    // PV: write own bf16 partial, then last-finishing block of the tile sums
    // both partials (bf16-symmetric -> order-independent), normalizes, writes out.
    float* Of = (float*)outs.c[0];
    unsigned short* myp = (unsigned short*)(z == 0 ? outs.c[1] : outs.c[2]);
    const unsigned short* otp = (const unsigned short*)(z == 0 ? outs.c[2] : outs.c[1]);
    const float* rsv = (const float*)outs.c[3];
    int* cnt = (int*)outs.c[4];
    const int tileid = (row0 >> 8) * gx + (col0 >> 7);
#pragma unroll
    for (int mf = 0; mf < 8; ++mf)
#pragma unroll
      for (int nf = 0; nf < 4; ++nf)
#pragma unroll
        for (int r = 0; r < 4; ++r)
          myp[(size_t)(row0 + wm * 128 + mf * 16 + er + r) * 1024 +
              (col0 + wn * 64 + nf * 16 + ec)] = f2bf_u16(acc[mf][nf][r]);
    __threadfence();                 // release: my stores visible device-wide
    __syncthreads();                 // all threads' fences done
    if (t == 0) lf = atomicAdd(cnt + tileid, 1);
    __syncthreads();
    if (lf == 1) {                   // we are the last producer for this tile
      __threadfence();               // acquire: other block's stores visible
#pragma unroll
      for (int mf = 0; mf < 8; ++mf) {
#pragma unroll
        for (int r = 0; r < 4; ++r) {
          const int m = row0 + wm * 128 + mf * 16 + er + r;
          const float inv = 1.0f / rsv[m];
#pragma unroll
          for (int nf = 0; nf < 4; ++nf) {
            const int n = col0 + wn * 64 + nf * 16 + ec;
            const float own = bf2f(f2bf_u16(acc[mf][nf][r]));   // match partial rounding
            Of[(size_t)m * 1024 + n] = (own + bf2f(otp[(size_t)m * 1024 + n])) * inv;
          }
        }
      }
    }
  } else if (EPI == 2) {
    // S: P = bf16(exp(scale*acc)); row-sum partials -> rsp[(col0>>7)*2+wn][m]
    unsigned short* Pb = (unsigned short*)outs.c[0];
    float* rsp = (float*)outs.c[1];
    const int ldc = outs.ldc0;
    const int rj = ((col0 >> 7) * 2 + wn) * 4096;
#pragma unroll
    for (int mf = 0; mf < 8; ++mf) {
#pragma unroll
      for (int r = 0; r < 4; ++r) {
        const int m = row0 + wm * 128 + mf * 16 + er + r;
        float rsum = 0.f;
#pragma unroll
        for (int nf = 0; nf < 4; ++nf) {
          const float e = __expf(acc[mf][nf][r] * scale);
          Pb[(size_t)m * ldc + (col0 + wn * 64 + nf * 16 + ec)] = f2bf_u16(e);
          rsum += e;
        }
        rsum += __shfl_xor(rsum, 1);
        rsum += __shfl_xor(rsum, 2);
        rsum += __shfl_xor(rsum, 4);
        rsum += __shfl_xor(rsum, 8);
        if (ec == 0) rsp[rj + m] = rsum;   // plain store, unique address
      }
    }
  } else {
    // QKV: q,k -> qkb [4096][2048]; v -> vT [1024][4096] (transposed)
    if (col0 < 2048) {
      unsigned short* qkb = (unsigned short*)outs.c[0];
#pragma unroll
      for (int mf = 0; mf < 8; ++mf)
#pragma unroll
        for (int nf = 0; nf < 4; ++nf)
#pragma unroll
          for (int r = 0; r < 4; ++r)
            qkb[(size_t)(row0 + wm * 128 + mf * 16 + er + r) * 2048 +
                (col0 + wn * 64 + nf * 16 + ec)] = f2bf_u16(acc[mf][nf][r]);
    } else {
      unsigned short* vT = (unsigned short*)outs.c[1];
#pragma unroll
      for (int mf = 0; mf < 8; ++mf)
#pragma unroll
        for (int nf = 0; nf < 4; ++nf) {
          const int n = (col0 - 2048) + wn * 64 + nf * 16 + ec;
          const int mb = row0 + wm * 128 + mf * 16 + er;
          ushort4 o = make_ushort4(f2bf_u16(acc[mf][nf][0]), f2bf_u16(acc[mf][nf][1]),
                                   f2bf_u16(acc[mf][nf][2]), f2bf_u16(acc[mf][nf][3]));
          *reinterpret_cast<ushort4*>(&vT[(size_t)n * 4096 + mb]) = o;
        }
    }
  }
}

extern "C" void kernel_launch(void* const* d_in, const int* in_sizes, int n_in,
                              void* d_out, int out_size, void* d_ws, size_t ws_size,
                              hipStream_t stream) {
  const float* x  = (const float*)d_in[0];
  const float* Wq = (const float*)d_in[1];
  const float* Wk = (const float*)d_in[2];
  const float* Wv = (const float*)d_in[3];
  float* out = (float*)d_out;

  const int N = 4096, D = 1024;

  // workspace (~80 MB):
  // [0,32)   P bf16 [4096][4096] = exp(scores)
  // [32,48)  qkb bf16 [4096][2048]  (q | k)
  // [48,56)  vT bf16 [1024][4096]
  // [56,64)  xb bf16 [4096][1024]; reused as p0 bf16 [4096][1024] after QKV
  // [64,70)  wb bf16 [3072][1024] (Wq;Wk;Wv)
  // [70,71)  rsp f32 [64][4096]
  // [71,..)  rs f32 [4096]; cnt int[128] at +16KB
  // [72,80)  p1 bf16 [4096][1024]
  char* ws = (char*)d_ws;
  unsigned short* P   = (unsigned short*)ws;
  unsigned short* qkb = (unsigned short*)(ws + (32u << 20));
  unsigned short* vT  = (unsigned short*)(ws + (48u << 20));
  unsigned short* xb  = (unsigned short*)(ws + (56u << 20));
  unsigned short* wb  = (unsigned short*)(ws + (64u << 20));
  float*          rsp = (float*)(ws + (70u << 20));
  float*          rs  = (float*)(ws + (71u << 20));
  int*            cnt = (int*)(ws + (71u << 20) + 16384);
  unsigned short* p0  = xb;   // dead after QKV
  unsigned short* p1  = (unsigned short*)(ws + (72u << 20));

  // fused casts + PV counter zeroing (block 7168)
  cast_all<<<7169, 256, 0, stream>>>(x, Wq, Wk, Wv, xb, wb, cnt);

  // qkv = x @ [Wq;Wk;Wv]^T : q,k -> qkb; v -> vT (transposed in epilogue)
  GemmOuts oq; oq.c[0] = qkb; oq.c[1] = vT; oq.c[2] = oq.c[3] = oq.c[4] = qkb; oq.ldc0 = 2048;
  gemm_bt<3><<<dim3(3 * D / 128, N / 256, 1), 256, 0, stream>>>(xb, wb, oq, D, D, D, 1.0f);

  // P = exp((q @ k^T)/32); rsp = row-sum partials (no atomics)
  GemmOuts os; os.c[0] = P; os.c[1] = rsp; os.c[2] = os.c[3] = os.c[4] = P; os.ldc0 = N;
  gemm_bt<2><<<dim3(N / 128, N / 256, 1), 256, 0, stream>>>(qkb, qkb + D, os, 2 * D, 2 * D, D, 0.03125f);

  // rs = sum of the 64 row-sum partials
  collapse_rs<<<16, 256, 0, stream>>>(rsp, rs);

  // out = (P @ v) / rs, split-K x2 with fused flag-based reduction
  GemmOuts op;
  op.c[0] = out; op.c[1] = p0; op.c[2] = p1; op.c[3] = rs; op.c[4] = cnt; op.ldc0 = D;
  gemm_bt<0><<<dim3(D / 128, N / 256, 2), 256, 0, stream>>>(P, vT, op, N, N, N / 2, 1.0f);
}

// Round 9
// 141.749 us; speedup vs baseline: 1.5615x; 1.5615x over previous
//
#include <hip/hip_runtime.h>

// SelfAttention: out = softmax((x Wq^T)(x Wk^T)^T / 32) (x Wv^T)
// N=4096, D=1024, f32 in/out; bf16 MFMA compute.
// GEMM v9 = v7 core (best measured): 256x128 tile, 4 waves, wave-tile 128x64,
// BK=32, 2-buffer 48 KiB LDS, prefetch-1 + counted vmcnt(6), conflict-free XOR
// swizzle, XCD block swizzle, 2 independent blocks/CU
// + T5 setprio(1) around the MFMA cluster (role-diverse 2-block/CU regime).
// r8's fused flag-reduction REVERTED (device-fence epilogue cost ~70 us).

typedef __attribute__((ext_vector_type(8))) __bf16 bf16x8;
typedef __attribute__((ext_vector_type(4))) float floatx4;

#define GLB_AS __attribute__((address_space(1)))
#define LDS_AS __attribute__((address_space(3)))

static __device__ __forceinline__ unsigned short f2bf_u16(float f) {
  union { float f; unsigned u; } x; x.f = f;
  unsigned r = x.u;
  r += 0x7fffu + ((r >> 16) & 1u);   // RNE
  return (unsigned short)(r >> 16);
}
static __device__ __forceinline__ float bf2f(unsigned short u) {
  union { unsigned u; float f; } x; x.u = ((unsigned)u) << 16; return x.f;
}

// ---------------- fused cast f32 -> bf16 (x + Wq + Wk + Wv) ----------------
__global__ __launch_bounds__(256) void cast_all(const float* __restrict__ x,
                                                const float* __restrict__ Wq,
                                                const float* __restrict__ Wk,
                                                const float* __restrict__ Wv,
                                                unsigned short* __restrict__ xb,
                                                unsigned short* __restrict__ wb) {
  const int i = blockIdx.x * 256 + threadIdx.x;   // float4 index
  const int NX4 = 4096 * 1024 / 4;
  const int NW4 = 1024 * 1024 / 4;
  const float* src; unsigned short* dst; int k;
  if (i < NX4)                { src = x;  dst = xb;                   k = i; }
  else if (i < NX4 + NW4)     { src = Wq; dst = wb;                   k = i - NX4; }
  else if (i < NX4 + 2 * NW4) { src = Wk; dst = wb + 1024 * 1024;     k = i - NX4 - NW4; }
  else                        { src = Wv; dst = wb + 2 * 1024 * 1024; k = i - NX4 - 2 * NW4; }
  float4 v = reinterpret_cast<const float4*>(src)[k];
  ushort4 o = make_ushort4(f2bf_u16(v.x), f2bf_u16(v.y), f2bf_u16(v.z), f2bf_u16(v.w));
  reinterpret_cast<ushort4*>(dst)[k] = o;
}

// ---------------- GEMM: C[M,N] = epi(scale * A[M,K] * B[N,K]^T) ----------------
// EPI: 0 = PV  (bf16 partial store to c[z])
//      2 = S   (bf16 store of exp to c[0]; per-(colblock,wave) row-sum partials to c[1])
//      3 = QKV (col0<2048: bf16 -> qkb c[0]; col0>=2048: transposed -> vT c[1])
struct GemmOuts { void* c[4]; int ldc[4]; };

template <int EPI>
__global__ __launch_bounds__(256, 2) void gemm_bt(const unsigned short* __restrict__ A,
                                                  const unsigned short* __restrict__ B,
                                                  GemmOuts outs, int lda, int ldb,
                                                  int klen, float scale) {
  // LDS: 2 bufs x (A [256][32] + B [128][32]) = 24576 elems = 48 KiB
  __shared__ unsigned short sh[24576];
  const int t = threadIdx.x;
  const int w = t >> 6, lane = t & 63;
  const int wm = w >> 1, wn = w & 1;        // 2x2 wave grid, wave tile 128x64
  // XCD-aware bijective block swizzle (nwg % 8 == 0 for all grids here)
  const int gx = gridDim.x;
  const int nwg = gx * gridDim.y;
  int bid = blockIdx.y * gx + blockIdx.x;
  bid = (bid & 7) * (nwg >> 3) + (bid >> 3);
  const int row0 = (bid / gx) * 256;
  const int col0 = (bid % gx) * 128;
  const int z = blockIdx.z;
  const int kstart = z * klen;
  const int NT = klen >> 5;                 // K-tiles of 32 (NT >= 2)

  // staging: 6 x 16B per thread per K-tile (A: 4 row-chunks of 64, B: 2).
  // Inverse-swizzled global col (rule 21): LDS linear dest, source pre-permuted.
  const int srow = t >> 2;                                  // 0..63
  const int scbe = (((t & 3) ^ ((t >> 3) & 3)) << 3);       // swizzled src col (elems)
  const unsigned short* gA0 = A + (size_t)(row0 + srow) * lda + kstart + scbe;
  const unsigned short* gA1 = gA0 + (size_t)64 * lda;
  const unsigned short* gA2 = gA0 + (size_t)128 * lda;
  const unsigned short* gA3 = gA0 + (size_t)192 * lda;
  const unsigned short* gB0 = B + (size_t)(col0 + srow) * ldb + kstart + scbe;
  const unsigned short* gB1 = gB0 + (size_t)64 * ldb;

#define STAGE(tl_) do { \
    const int bb_ = ((tl_) & 1) * 12288; \
    __builtin_amdgcn_global_load_lds((const GLB_AS void*)(gA0 + (tl_) * 32), \
        (LDS_AS void*)&sh[bb_ + t * 8], 16, 0, 0); \
    __builtin_amdgcn_global_load_lds((const GLB_AS void*)(gA1 + (tl_) * 32), \
        (LDS_AS void*)&sh[bb_ + 2048 + t * 8], 16, 0, 0); \
    __builtin_amdgcn_global_load_lds((const GLB_AS void*)(gA2 + (tl_) * 32), \
        (LDS_AS void*)&sh[bb_ + 4096 + t * 8], 16, 0, 0); \
    __builtin_amdgcn_global_load_lds((const GLB_AS void*)(gA3 + (tl_) * 32), \
        (LDS_AS void*)&sh[bb_ + 6144 + t * 8], 16, 0, 0); \
    __builtin_amdgcn_global_load_lds((const GLB_AS void*)(gB0 + (tl_) * 32), \
        (LDS_AS void*)&sh[bb_ + 8192 + t * 8], 16, 0, 0); \
    __builtin_amdgcn_global_load_lds((const GLB_AS void*)(gB1 + (tl_) * 32), \
        (LDS_AS void*)&sh[bb_ + 10240 + t * 8], 16, 0, 0); \
  } while (0)

  // ds_read element offsets (swizzled; same conflict-free family as r2-r7)
  const int fr = lane & 15;
  const int sg = (((lane >> 4) ^ ((lane >> 1) & 3)) << 3);
  int aofs[8], bofs[4];
#pragma unroll
  for (int mf = 0; mf < 8; ++mf) aofs[mf] = ((wm * 128 + mf * 16 + fr) << 5) + sg;
#pragma unroll
  for (int nf = 0; nf < 4; ++nf) bofs[nf] = 8192 + ((wn * 64 + nf * 16 + fr) << 5) + sg;

  floatx4 acc[8][4] = {};

  STAGE(0);

  for (int tile = 0; tile < NT; ++tile) {
    if (tile + 1 < NT) {
      STAGE(tile + 1);
      asm volatile("s_waitcnt vmcnt(6)" ::: "memory");   // tile's own 6 loads landed
    } else {
      asm volatile("s_waitcnt vmcnt(0)" ::: "memory");
    }
    __builtin_amdgcn_s_barrier();   // buf[tile&1] ready for all waves

    const int bo = (tile & 1) * 12288;
    bf16x8 af[8], bf[4];
#pragma unroll
    for (int mf = 0; mf < 8; ++mf) af[mf] = *(const bf16x8*)&sh[bo + aofs[mf]];
#pragma unroll
    for (int nf = 0; nf < 4; ++nf) bf[nf] = *(const bf16x8*)&sh[bo + bofs[nf]];
    // T5: 2 independent blocks/CU = role-diverse waves on each SIMD ->
    // prefer the MFMA-issuing wave while the sibling block stages/reads.
    __builtin_amdgcn_s_setprio(1);
#pragma unroll
    for (int mf = 0; mf < 8; ++mf)
#pragma unroll
      for (int nf = 0; nf < 4; ++nf)
        acc[mf][nf] = __builtin_amdgcn_mfma_f32_16x16x32_bf16(af[mf], bf[nf], acc[mf][nf], 0, 0, 0);
    __builtin_amdgcn_s_setprio(0);

    __builtin_amdgcn_s_barrier();   // all waves done reading buf[tile&1]
  }
#undef STAGE

  // epilogue: C col = lane&15, row = (lane>>4)*4 + r  [m89-verified]
  const int er = (lane >> 4) * 4;
  const int ec = lane & 15;

  if (EPI == 0) {
    // PV: bf16 partial store
    unsigned short* Cb = (unsigned short*)outs.c[z];
    const int ldc = outs.ldc[z];
#pragma unroll
    for (int mf = 0; mf < 8; ++mf)
#pragma unroll
      for (int nf = 0; nf < 4; ++nf)
#pragma unroll
        for (int r = 0; r < 4; ++r)
          Cb[(size_t)(row0 + wm * 128 + mf * 16 + er + r) * ldc +
             (col0 + wn * 64 + nf * 16 + ec)] = f2bf_u16(acc[mf][nf][r] * scale);
  } else if (EPI == 2) {
    // S: P = bf16(exp(scale*acc)); row-sum partials -> rsp[(col0>>7)*2+wn][m]
    unsigned short* Pb = (unsigned short*)outs.c[0];
    float* rsp = (float*)outs.c[1];
    const int ldc = outs.ldc[0];
    const int rj = ((col0 >> 7) * 2 + wn) * 4096;
#pragma unroll
    for (int mf = 0; mf < 8; ++mf) {
#pragma unroll
      for (int r = 0; r < 4; ++r) {
        const int m = row0 + wm * 128 + mf * 16 + er + r;
        float rsum = 0.f;
#pragma unroll
        for (int nf = 0; nf < 4; ++nf) {
          const float e = __expf(acc[mf][nf][r] * scale);
          Pb[(size_t)m * ldc + (col0 + wn * 64 + nf * 16 + ec)] = f2bf_u16(e);
          rsum += e;
        }
        rsum += __shfl_xor(rsum, 1);
        rsum += __shfl_xor(rsum, 2);
        rsum += __shfl_xor(rsum, 4);
        rsum += __shfl_xor(rsum, 8);
        if (ec == 0) rsp[rj + m] = rsum;   // plain store, unique address
      }
    }
  } else {
    // QKV: q,k -> qkb [4096][2048]; v -> vT [1024][4096] (transposed)
    if (col0 < 2048) {
      unsigned short* qkb = (unsigned short*)outs.c[0];
#pragma unroll
      for (int mf = 0; mf < 8; ++mf)
#pragma unroll
        for (int nf = 0; nf < 4; ++nf)
#pragma unroll
          for (int r = 0; r < 4; ++r)
            qkb[(size_t)(row0 + wm * 128 + mf * 16 + er + r) * 2048 +
                (col0 + wn * 64 + nf * 16 + ec)] = f2bf_u16(acc[mf][nf][r]);
    } else {
      unsigned short* vT = (unsigned short*)outs.c[1];
#pragma unroll
      for (int mf = 0; mf < 8; ++mf)
#pragma unroll
        for (int nf = 0; nf < 4; ++nf) {
          const int n = (col0 - 2048) + wn * 64 + nf * 16 + ec;
          const int mb = row0 + wm * 128 + mf * 16 + er;
          ushort4 o = make_ushort4(f2bf_u16(acc[mf][nf][0]), f2bf_u16(acc[mf][nf][1]),
                                   f2bf_u16(acc[mf][nf][2]), f2bf_u16(acc[mf][nf][3]));
          *reinterpret_cast<ushort4*>(&vT[(size_t)n * 4096 + mb]) = o;
        }
    }
  }
}

// ---------------- reduce: out[row] = (p0+p1)[row] / sum_j rsp[j][row] ----------------
__global__ __launch_bounds__(256) void reduce_pv(float* __restrict__ out,
                                                 const unsigned short* __restrict__ p0,
                                                 const unsigned short* __restrict__ p1,
                                                 const float* __restrict__ rsp) {
  const int row = blockIdx.x;
  const int lane = threadIdx.x & 63;
  float s = rsp[lane * 4096 + row];
#pragma unroll
  for (int off = 32; off >= 1; off >>= 1) s += __shfl_xor(s, off);
  const float inv = 1.0f / s;
  const int idx = row * 256 + threadIdx.x;   // ushort4 / float4 index
  ushort4 a = ((const ushort4*)p0)[idx];
  ushort4 b = ((const ushort4*)p1)[idx];
  float4 o;
  o.x = (bf2f(a.x) + bf2f(b.x)) * inv;
  o.y = (bf2f(a.y) + bf2f(b.y)) * inv;
  o.z = (bf2f(a.z) + bf2f(b.z)) * inv;
  o.w = (bf2f(a.w) + bf2f(b.w)) * inv;
  ((float4*)out)[idx] = o;
}

extern "C" void kernel_launch(void* const* d_in, const int* in_sizes, int n_in,
                              void* d_out, int out_size, void* d_ws, size_t ws_size,
                              hipStream_t stream) {
  const float* x  = (const float*)d_in[0];
  const float* Wq = (const float*)d_in[1];
  const float* Wk = (const float*)d_in[2];
  const float* Wv = (const float*)d_in[3];
  float* out = (float*)d_out;

  const int N = 4096, D = 1024;

  // workspace (~80 MB):
  // [0,32)   P bf16 [4096][4096] = exp(scores)
  // [32,48)  qkb bf16 [4096][2048]  (q | k)
  // [48,56)  vT bf16 [1024][4096]
  // [56,64)  xb bf16 [4096][1024]; reused as p0 bf16 [4096][1024] after QKV
  // [64,70)  wb bf16 [3072][1024] (Wq;Wk;Wv)
  // [70,71)  rsp f32 [64][4096] row-sum partials
  // [72,80)  p1 bf16 [4096][1024]
  char* ws = (char*)d_ws;
  unsigned short* P   = (unsigned short*)ws;
  unsigned short* qkb = (unsigned short*)(ws + (32u << 20));
  unsigned short* vT  = (unsigned short*)(ws + (48u << 20));
  unsigned short* xb  = (unsigned short*)(ws + (56u << 20));
  unsigned short* wb  = (unsigned short*)(ws + (64u << 20));
  float*          rsp = (float*)(ws + (70u << 20));
  unsigned short* p0  = xb;   // dead after QKV
  unsigned short* p1  = (unsigned short*)(ws + (72u << 20));

  // fused casts
  cast_all<<<7168, 256, 0, stream>>>(x, Wq, Wk, Wv, xb, wb);

  // qkv = x @ [Wq;Wk;Wv]^T : q,k -> qkb; v -> vT (transposed in epilogue)
  GemmOuts oq; oq.c[0] = qkb; oq.c[1] = vT; oq.c[2] = oq.c[3] = qkb;
  oq.ldc[0] = 2048; oq.ldc[1] = 4096; oq.ldc[2] = oq.ldc[3] = 2048;
  gemm_bt<3><<<dim3(3 * D / 128, N / 256, 1), 256, 0, stream>>>(xb, wb, oq, D, D, D, 1.0f);

  // P = exp((q @ k^T)/32); rsp = row-sum partials (no atomics)
  GemmOuts os; os.c[0] = P; os.c[1] = rsp; os.c[2] = os.c[3] = P;
  os.ldc[0] = N; os.ldc[1] = 0; os.ldc[2] = os.ldc[3] = N;
  gemm_bt<2><<<dim3(N / 128, N / 256, 1), 256, 0, stream>>>(qkb, qkb + D, os, 2 * D, 2 * D, D, 0.03125f);

  // partials = P @ v, split-K x2 (bf16): z0 -> p0, z1 -> p1
  GemmOuts op;
  op.c[0] = p0; op.ldc[0] = D;
  op.c[1] = p1; op.ldc[1] = D;
  op.c[2] = p0; op.ldc[2] = D;
  op.c[3] = p1; op.ldc[3] = D;
  gemm_bt<0><<<dim3(D / 128, N / 256, 2), 256, 0, stream>>>(P, vT, op, N, N, N / 2, 1.0f);

  // out = (p0+p1) / rowsum
  reduce_pv<<<N, 256, 0, stream>>>(out, p0, p1, rsp);
}